// Round 5
// baseline (744.027 us; speedup 1.0000x reference)
//
#include <hip/hip_runtime.h>
#include <math.h>

#define PP 16
#define VV 32
#define DD 686

__device__ __forceinline__ double clampd(double x, double lo, double hi) {
    return fmin(fmax(x, lo), hi);
}
__device__ __forceinline__ double powd(double b, double e) {
    return exp2(e * log2(b));   // b>0 always (clamped >=1e-30)
}

// support value clip(h*maxz) for one query direction against VV local verts (f32 storage, f64 math)
__device__ double spt_support_d(const float* __restrict__ sv, double pe,
                                double dx, double dy, double dz)
{
    double z[VV];
    double maxz = -1e300;
#pragma unroll
    for (int k = 0; k < VV; ++k) {
        double zz = (double)sv[3*k+0]*dx + (double)sv[3*k+1]*dy + (double)sv[3*k+2]*dz;
        z[k] = zz;
        maxz = fmax(maxz, zz);
    }
    maxz = clampd(maxz, 1e-30, 1e30);
    double kk = 1.0 / maxz;
    double sum = 0.0;
#pragma unroll
    for (int k = 0; k < VV; ++k) {
        double zm = clampd(fmax(z[k], 0.0) * kk, 1e-30, 1e30);
        sum += powd(zm, pe);
    }
    double h = powd(sum, 1.0 / pe);
    return clampd(h * maxz, -1e30, 1e30);
}

// ---- directions (match numpy f64 linspace + trig, cast f32) ----
__global__ void k_dirs(float* __restrict__ dirs)
{
    int idx = blockIdx.x * blockDim.x + threadIdx.x;
    if (idx >= DD) return;
    int i, j;
    if (idx < 684)      { i = idx / 38 + 1; j = idx - (idx / 38) * 38; }
    else if (idx == 684){ i = 0;  j = 0; }
    else                { i = 19; j = 0; }
    const double pi = 3.14159265358979323846;
    double th1 = -pi * 0.5 + (double)i * (pi / 19.0);
    double th2 = -pi       + (double)j * (pi / 19.0);
    double c1 = cos(th1), s1 = sin(th1);
    double c2 = cos(th2), s2 = sin(th2);
    dirs[3*idx+0] = (float)(c1 * c2);
    dirs[3*idx+1] = (float)(c1 * s2);
    dirs[3*idx+2] = (float)(s1);
}

// ---- per-shape prep: mean (f64), local verts, pe ----
__global__ void k_prep(const float* __restrict__ verts, const float* __restrict__ smooth,
                       double* __restrict__ dmean, float* __restrict__ flocal,
                       float* __restrict__ fpe, int BP)
{
    int bp = blockIdx.x * blockDim.x + threadIdx.x;
    if (bp >= BP) return;
    const float* vv = verts + (size_t)bp * VV * 3;
    double sx = 0.0, sy = 0.0, sz = 0.0;
#pragma unroll
    for (int k = 0; k < VV; ++k) {
        sx += (double)vv[3*k+0];
        sy += (double)vv[3*k+1];
        sz += (double)vv[3*k+2];
    }
    double mx = sx / 32.0, my = sy / 32.0, mz = sz / 32.0;
    dmean[3*bp+0] = mx; dmean[3*bp+1] = my; dmean[3*bp+2] = mz;
    float* lv = flocal + (size_t)bp * VV * 3;
#pragma unroll
    for (int k = 0; k < VV; ++k) {
        lv[3*k+0] = (float)((double)vv[3*k+0] - mx);
        lv[3*k+1] = (float)((double)vv[3*k+1] - my);
        lv[3*k+2] = (float)((double)vv[3*k+2] - mz);
    }
    fpe[bp] = smooth[bp];
}

// ---- scale = clip(max_d support, 1e-10, 10); also writes x output (f32) ----
__global__ void __launch_bounds__(256) k_scale_x(
        const float* __restrict__ dirs, const float* __restrict__ flocal,
        const float* __restrict__ fpe, double* __restrict__ dscale,
        float* __restrict__ out2)
{
    int bp = blockIdx.x;
    __shared__ float sv[VV*3];
    __shared__ double red[4];
    int tid = threadIdx.x;
    if (tid < VV*3) sv[tid] = flocal[(size_t)bp*VV*3 + tid];
    __syncthreads();
    double pe = (double)fpe[bp];
    double m = -1e300;
    for (int dd = tid; dd < DD; dd += 256) {
        float dxf = dirs[3*dd+0], dyf = dirs[3*dd+1], dzf = dirs[3*dd+2];
        double hs = spt_support_d(sv, pe, (double)dxf, (double)dyf, (double)dzf);
        m = fmax(m, hs);
        float* xp = out2 + ((size_t)bp * DD + dd) * 3;
        xp[0] = dxf;
        xp[1] = dyf;
        xp[2] = dzf;
    }
#pragma unroll
    for (int o = 32; o > 0; o >>= 1) m = fmax(m, __shfl_down(m, o));
    if ((tid & 63) == 0) red[tid >> 6] = m;
    __syncthreads();
    if (tid == 0) {
        m = fmax(fmax(red[0], red[1]), fmax(red[2], red[3]));
        dscale[bp] = clampd(m, 1e-10, 10.0);
    }
}

// ---- surf points (dhdz path), f64, f32 output ----
__global__ void __launch_bounds__(256) k_surfpts(
        const float* __restrict__ dirs, const float* __restrict__ flocal,
        const double* __restrict__ dmean, const float* __restrict__ fpe,
        const double* __restrict__ dscale,
        float* __restrict__ fsurf, float* __restrict__ out4)
{
    int bp = blockIdx.x;
    __shared__ float sv[VV*3];
    int tid = threadIdx.x;
    if (tid < VV*3) sv[tid] = flocal[(size_t)bp*VV*3 + tid];
    __syncthreads();
    double pe = (double)fpe[bp];
    double sc = dscale[bp];
    double m0 = dmean[3*bp+0], m1 = dmean[3*bp+1], m2 = dmean[3*bp+2];
    for (int dd = tid; dd < DD; dd += 256) {
        double xd = (double)dirs[3*dd+0], yd = (double)dirs[3*dd+1], zd = (double)dirs[3*dd+2];
        // pts = x*scale + mean ; local = pts - mean  (exact np order)
        double lx = (xd * sc + m0) - m0;
        double ly = (yd * sc + m1) - m1;
        double lz = (zd * sc + m2) - m2;
        double n2 = clampd(lx*lx + ly*ly + lz*lz, 1e-40, 1e40);
        double nrm = sqrt(n2);
        double dx = lx / nrm, dy = ly / nrm, dz = lz / nrm;

        double z[VV];
        double maxz = -1e300;
#pragma unroll
        for (int k = 0; k < VV; ++k) {
            double zz = (double)sv[3*k+0]*dx + (double)sv[3*k+1]*dy + (double)sv[3*k+2]*dz;
            z[k] = zz;
            maxz = fmax(maxz, zz);
        }
        maxz = clampd(maxz, 1e-30, 1e30);
        double kk = 1.0 / maxz;
        double sum = 0.0;
#pragma unroll
        for (int k = 0; k < VV; ++k) {
            double zm = clampd(fmax(z[k], 0.0) * kk, 1e-30, 1e30);
            z[k] = zm;
            sum += powd(zm, pe);
        }
        double h = powd(sum, 1.0 / pe);
        double s = clampd(h, 1e-30, 1e30);
        double sxx = 0.0, syy = 0.0, szz = 0.0;
#pragma unroll
        for (int k = 0; k < VV; ++k) {
            double dh = clampd(powd(z[k] / s, pe - 1.0), 1e-30, 1e30);
            sxx += dh * (double)sv[3*k+0];
            syy += dh * (double)sv[3*k+1];
            szz += dh * (double)sv[3*k+2];
        }
        sxx += m0; syy += m1; szz += m2;
        float* spp = fsurf + ((size_t)bp * DD + dd) * 3;
        spp[0] = (float)sxx; spp[1] = (float)syy; spp[2] = (float)szz;
        float* op = out4 + ((size_t)bp * DD + dd) * 3;
        op[0] = (float)sxx; op[1] = (float)syy; op[2] = (float)szz;
    }
}

// ---- overlap: P x P pairs per batch, f64, f32 output ----
__global__ void __launch_bounds__(256) k_overlap(
        const float* __restrict__ flocal, const double* __restrict__ dmean,
        const float* __restrict__ fpe, float* __restrict__ out0)
{
    int b = blockIdx.x;
    __shared__ float  sv[PP*VV*3];
    __shared__ double smd[PP*3];
    __shared__ float  spe[PP];
    __shared__ double shd[PP*PP];
    int tid = threadIdx.x;
    for (int t = tid; t < PP*VV*3; t += 256) sv[t] = flocal[(size_t)b*PP*VV*3 + t];
    if (tid < PP*3) smd[tid] = dmean[(size_t)b*PP*3 + tid];
    if (tid < PP)   spe[tid] = fpe[b*PP + tid];
    __syncthreads();
    int i = tid >> 4, j = tid & 15;
    double tx = smd[3*j+0] - smd[3*i+0];
    double ty = smd[3*j+1] - smd[3*i+1];
    double tz = smd[3*j+2] - smd[3*i+2];
    double dn2 = clampd(tx*tx + ty*ty + tz*tz, 1e-20, 1e20);
    double dn = sqrt(dn2);
    double dx, dy, dz;
    if (i == j) { dx = 1.0; dy = 0.0; dz = 0.0; }
    else        { dx = tx/dn; dy = ty/dn; dz = tz/dn; }
    shd[tid] = spt_support_d(&sv[i*VV*3], (double)spe[i], dx, dy, dz);
    __syncthreads();
    double sep = dn - shd[i*16 + j] - shd[j*16 + i];
    double ov = (i == j) ? 0.0 : fmax(-sep, 0.0);
    out0[(size_t)b*PP*PP + tid] = (float)ov;
}

// ---- generic distance kernel: dist = nrm - support, f64, f32 output ----
__global__ void __launch_bounds__(256) k_dist(
        const float* __restrict__ pts, int N,
        const float* __restrict__ flocal, const double* __restrict__ dmean,
        const float* __restrict__ fpe, float* __restrict__ outp)
{
    int bp = blockIdx.x;
    int b  = bp >> 4;
    __shared__ float sv[VV*3];
    int tid = threadIdx.x;
    if (tid < VV*3) sv[tid] = flocal[(size_t)bp*VV*3 + tid];
    __syncthreads();
    double pe = (double)fpe[bp];
    double m0 = dmean[3*bp+0], m1 = dmean[3*bp+1], m2 = dmean[3*bp+2];
    int n = blockIdx.y * 256 + tid;
    if (n >= N) return;
    const float* pp = pts + ((size_t)b * N + n) * 3;
    double lx = (double)pp[0] - m0;
    double ly = (double)pp[1] - m1;
    double lz = (double)pp[2] - m2;
    double n2 = clampd(lx*lx + ly*ly + lz*lz, 1e-40, 1e40);
    double nrm = sqrt(n2);
    double dx = lx / nrm, dy = ly / nrm, dz = lz / nrm;
    double hs = spt_support_d(sv, pe, dx, dy, dz);
    outp[(size_t)bp * N + n] = (float)(nrm - hs);
}

// ---- surf distance with normal filter and diagonal=100, f64, f32 output ----
__global__ void __launch_bounds__(256) k_surfdist(
        const float* __restrict__ fsurf, const float* __restrict__ dirs,
        const float* __restrict__ flocal, const double* __restrict__ dmean,
        const float* __restrict__ fpe, const double* __restrict__ dscale,
        float* __restrict__ out3)
{
    int bp = blockIdx.x;
    int b  = bp >> 4;
    int i  = bp & 15;
    __shared__ float sv[VV*3];
    int tid = threadIdx.x;
    if (tid < VV*3) sv[tid] = flocal[(size_t)bp*VV*3 + tid];
    __syncthreads();
    double pe = (double)fpe[bp];
    double sc = dscale[bp];
    double mi0 = dmean[3*bp+0], mi1 = dmean[3*bp+1], mi2 = dmean[3*bp+2];
    int q = blockIdx.y * 256 + tid;
    if (q >= PP*DD) return;
    int j  = q / DD;
    int dd = q - j * DD;
    // normal_i at direction dd: d = ((x*s_i + m_i) - m_i)/nrm, exact np order
    double xd = (double)dirs[3*dd+0], yd = (double)dirs[3*dd+1], zd = (double)dirs[3*dd+2];
    double nlx = (xd * sc + mi0) - mi0;
    double nly = (yd * sc + mi1) - mi1;
    double nlz = (zd * sc + mi2) - mi2;
    double nn2 = clampd(nlx*nlx + nly*nly + nlz*nlz, 1e-40, 1e40);
    double nnr = sqrt(nn2);
    double ndx = nlx / nnr, ndy = nly / nnr, ndz = nlz / nnr;
    const double* mj = dmean + (size_t)(b*PP + j) * 3;
    double tx = mj[0] - mi0, ty = mj[1] - mi1, tz = mj[2] - mi2;
    double nf = tx*ndx + ty*ndy + tz*ndz;
    double dist;
    if (i == j || nf < 0.0) {
        dist = 100.0;
    } else {
        const float* sp = fsurf + ((size_t)b * PP * DD + q) * 3;
        double lx = (double)sp[0] - mi0;
        double ly = (double)sp[1] - mi1;
        double lz = (double)sp[2] - mi2;
        double n2 = clampd(lx*lx + ly*ly + lz*lz, 1e-40, 1e40);
        double nrm = sqrt(n2);
        double dx = lx / nrm, dy = ly / nrm, dz = lz / nrm;
        double hs = spt_support_d(sv, pe, dx, dy, dz);
        dist = nrm - hs;
    }
    out3[(size_t)bp * PP * DD + q] = (float)dist;
}

extern "C" void kernel_launch(void* const* d_in, const int* in_sizes, int n_in,
                              void* d_out, int out_size, void* d_ws, size_t ws_size,
                              hipStream_t stream)
{
    // ---- runtime input binding by size (robust to ordering / extra DIRS input) ----
    const float* verts  = nullptr;
    const float* smooth = nullptr;
    const float* pcb    = nullptr;
    const float* nsb    = nullptr;
    const float* ob     = nullptr;
    const float* dirsin = nullptr;
    int Bv = 8, BP = 128, NPCv = 16384, NNSv = 8192, NOUTv = 8192;

    {
        int si = 0;
        for (int i = 1; i < n_in; ++i) if (in_sizes[i] < in_sizes[si]) si = i;
        int bp = in_sizes[si];
        bool ok = (bp > 0) && (bp % PP == 0);
        int rem[8]; int nrem = 0;
        const float* vcand = nullptr; const float* dcand = nullptr;
        if (ok) {
            for (int i = 0; i < n_in && i < 8; ++i) {
                if (i == si) continue;
                if (!vcand && in_sizes[i] == bp * VV * 3) { vcand = (const float*)d_in[i]; continue; }
                if (!dcand && in_sizes[i] == DD * 3)      { dcand = (const float*)d_in[i]; continue; }
                rem[nrem++] = i;
            }
        }
        if (ok && vcand && nrem == 3) {
            int pci = rem[0];
            for (int r = 1; r < 3; ++r) if (in_sizes[rem[r]] > in_sizes[pci]) pci = rem[r];
            int oth[2]; int no = 0;
            for (int r = 0; r < 3; ++r) if (rem[r] != pci) oth[no++] = rem[r];
            int B = bp / PP;
            int npc = in_sizes[pci] / (3 * B);
            int nns = in_sizes[oth[0]] / (3 * B);
            int nou = in_sizes[oth[1]] / (3 * B);
            if (npc > 0 && nns > 0 && nou > 0) {
                smooth = (const float*)d_in[si];
                verts  = vcand;
                dirsin = dcand;
                pcb    = (const float*)d_in[pci];
                nsb    = (const float*)d_in[oth[0]];
                ob     = (const float*)d_in[oth[1]];
                Bv = B; BP = bp; NPCv = npc; NNSv = nns; NOUTv = nou;
            }
        }
        if (!verts) {   // fallback: dict order, reference shapes
            verts  = (const float*)d_in[0];
            smooth = (const float*)d_in[1];
            pcb    = (const float*)d_in[2];
            nsb    = (const float*)d_in[3];
            ob     = (const float*)d_in[4];
            Bv = 8; BP = 128; NPCv = 16384; NNSv = 8192; NOUTv = 8192;
        }
    }

    // ---- workspace carve (mixed f64/f32), ~1.1 MB at B=8 ----
    double* dmean  = (double*)d_ws;            // 3*BP
    double* dscale = dmean + 3*(size_t)BP;     // BP   (byte off 24*BP)
    float*  fdirs  = (float*)(dscale + BP);    // 2058 (byte off 32*BP, 8-aligned)
    float*  fpe    = fdirs + DD*3;             // BP
    float*  flocal = fpe + BP;                 // 96*BP
    float*  fsurf  = flocal + 96*(size_t)BP;   // 3*DD*BP

    // ---- output offsets (runtime, f32 elements) ----
    float* out = (float*)d_out;
    size_t o0 = 0;
    size_t o1 = o0 + (size_t)Bv*PP*PP;
    size_t o2 = o1 + (size_t)BP*NPCv;
    size_t o3 = o2 + (size_t)BP*DD*3;
    size_t o4 = o3 + (size_t)BP*PP*DD;
    size_t o5 = o4 + (size_t)BP*DD*3;
    size_t o6 = o5 + (size_t)BP*NNSv;

    const float* dirs = dirsin ? dirsin : fdirs;
    if (!dirsin) k_dirs<<<dim3(3), 256, 0, stream>>>(fdirs);
    k_prep<<<dim3((BP + 127)/128), 128, 0, stream>>>(verts, smooth, dmean, flocal, fpe, BP);
    k_scale_x<<<dim3(BP), 256, 0, stream>>>(dirs, flocal, fpe, dscale, out + o2);
    k_surfpts<<<dim3(BP), 256, 0, stream>>>(dirs, flocal, dmean, fpe, dscale, fsurf, out + o4);
    k_overlap<<<dim3(Bv), 256, 0, stream>>>(flocal, dmean, fpe, out + o0);
    k_dist<<<dim3(BP, (NPCv + 255)/256), 256, 0, stream>>>(pcb, NPCv, flocal, dmean, fpe, out + o1);
    k_dist<<<dim3(BP, (NNSv + 255)/256), 256, 0, stream>>>(nsb, NNSv, flocal, dmean, fpe, out + o5);
    k_dist<<<dim3(BP, (NOUTv + 255)/256), 256, 0, stream>>>(ob, NOUTv, flocal, dmean, fpe, out + o6);
    k_surfdist<<<dim3(BP, (PP*DD + 255)/256), 256, 0, stream>>>(fsurf, dirs, flocal, dmean,
                                                                fpe, dscale, out + o3);
}

// Round 6
// 160.156 us; speedup vs baseline: 4.6456x; 4.6456x over previous
//
#include <hip/hip_runtime.h>
#include <math.h>

#define PP 16
#define VV 32
#define DD 686

__device__ __forceinline__ float clampf(float x, float lo, float hi) {
    return fminf(fmaxf(x, lo), hi);
}
__device__ __forceinline__ double clampd(double x, double lo, double hi) {
    return fmin(fmax(x, lo), hi);
}
__device__ __forceinline__ float fexp2(float x) { return __builtin_amdgcn_exp2f(x); }
__device__ __forceinline__ float flog2(float x) { return __builtin_amdgcn_logf(x); }   // log base-2
__device__ __forceinline__ float frcp (float x) { return __builtin_amdgcn_rcpf(x); }
__device__ __forceinline__ float frsq (float x) { return __builtin_amdgcn_rsqf(x); }

// support value clip(h*maxz) for one query direction against VV local verts (all f32, hw transc)
__device__ __forceinline__ float spt_support_f(const float* __restrict__ sv, float pe, float inv_pe,
                                               float dx, float dy, float dz)
{
    float z[VV];
    float maxz = -1e38f;
#pragma unroll
    for (int k = 0; k < VV; ++k) {
        float zz = sv[3*k+0]*dx + sv[3*k+1]*dy + sv[3*k+2]*dz;
        z[k] = zz;
        maxz = fmaxf(maxz, zz);
    }
    maxz = clampf(maxz, 1e-30f, 1e30f);
    float kk = frcp(maxz);
    float sum = 0.0f;
#pragma unroll
    for (int k = 0; k < VV; ++k) {
        float zm = clampf(fmaxf(z[k], 0.0f) * kk, 1e-30f, 1e30f);
        sum += fexp2(pe * flog2(zm));
    }
    float h = fexp2(flog2(sum) * inv_pe);
    return clampf(h * maxz, -1e30f, 1e30f);
}

// ---- directions (match numpy f64 linspace + trig, cast f32) ----
__global__ void k_dirs(float* __restrict__ dirs)
{
    int idx = blockIdx.x * blockDim.x + threadIdx.x;
    if (idx >= DD) return;
    int i, j;
    if (idx < 684)      { i = idx / 38 + 1; j = idx - (idx / 38) * 38; }
    else if (idx == 684){ i = 0;  j = 0; }
    else                { i = 19; j = 0; }
    const double pi = 3.14159265358979323846;
    double th1 = -pi * 0.5 + (double)i * (pi / 19.0);
    double th2 = -pi       + (double)j * (pi / 19.0);
    dirs[3*idx+0] = (float)(cos(th1) * cos(th2));
    dirs[3*idx+1] = (float)(cos(th1) * sin(th2));
    dirs[3*idx+2] = (float)(sin(th1));
}

// ---- per-shape prep: mean (f64 + f32 copies), local verts, pe, 1/pe ----
__global__ void k_prep(const float* __restrict__ verts, const float* __restrict__ smooth,
                       double* __restrict__ dmean, float* __restrict__ fmean,
                       float* __restrict__ flocal, float* __restrict__ fpe,
                       float* __restrict__ finvpe, int BP)
{
    int bp = blockIdx.x * blockDim.x + threadIdx.x;
    if (bp >= BP) return;
    const float* vv = verts + (size_t)bp * VV * 3;
    double sx = 0.0, sy = 0.0, sz = 0.0;
#pragma unroll
    for (int k = 0; k < VV; ++k) {
        sx += (double)vv[3*k+0];
        sy += (double)vv[3*k+1];
        sz += (double)vv[3*k+2];
    }
    double mx = sx / 32.0, my = sy / 32.0, mz = sz / 32.0;
    dmean[3*bp+0] = mx; dmean[3*bp+1] = my; dmean[3*bp+2] = mz;
    fmean[3*bp+0] = (float)mx; fmean[3*bp+1] = (float)my; fmean[3*bp+2] = (float)mz;
    float* lv = flocal + (size_t)bp * VV * 3;
#pragma unroll
    for (int k = 0; k < VV; ++k) {
        lv[3*k+0] = (float)((double)vv[3*k+0] - mx);
        lv[3*k+1] = (float)((double)vv[3*k+1] - my);
        lv[3*k+2] = (float)((double)vv[3*k+2] - mz);
    }
    float pe = smooth[bp];
    fpe[bp] = pe;
    finvpe[bp] = 1.0f / pe;
}

// ---- scale = clip(max_d support, 1e-10, 10); also writes x output (f32) ----
__global__ void __launch_bounds__(256) k_scale_x(
        const float* __restrict__ dirs, const float* __restrict__ flocal,
        const float* __restrict__ fpe, const float* __restrict__ finvpe,
        double* __restrict__ dscale, float* __restrict__ fscale,
        float* __restrict__ out2)
{
    int bp = blockIdx.x;
    __shared__ float sv[VV*3];
    __shared__ float red[4];
    int tid = threadIdx.x;
    if (tid < VV*3) sv[tid] = flocal[(size_t)bp*VV*3 + tid];
    __syncthreads();
    float pe = fpe[bp], ipe = finvpe[bp];
    float m = -1e38f;
    for (int dd = tid; dd < DD; dd += 256) {
        float dxf = dirs[3*dd+0], dyf = dirs[3*dd+1], dzf = dirs[3*dd+2];
        float hs = spt_support_f(sv, pe, ipe, dxf, dyf, dzf);
        m = fmaxf(m, hs);
        float* xp = out2 + ((size_t)bp * DD + dd) * 3;
        xp[0] = dxf; xp[1] = dyf; xp[2] = dzf;
    }
#pragma unroll
    for (int o = 32; o > 0; o >>= 1) m = fmaxf(m, __shfl_down(m, o));
    if ((tid & 63) == 0) red[tid >> 6] = m;
    __syncthreads();
    if (tid == 0) {
        m = fmaxf(fmaxf(red[0], red[1]), fmaxf(red[2], red[3]));
        m = clampf(m, 1e-10f, 10.0f);
        fscale[bp] = m;
        dscale[bp] = (double)m;
    }
}

// ---- surf points (dhdz path), f32, log2-reuse ----
__global__ void __launch_bounds__(256) k_surfpts(
        const float* __restrict__ dirs, const float* __restrict__ flocal,
        const float* __restrict__ fmean, const float* __restrict__ fpe,
        const float* __restrict__ finvpe, const float* __restrict__ fscale,
        float* __restrict__ fsurf, float* __restrict__ out4)
{
    int bp = blockIdx.x;
    __shared__ float sv[VV*3];
    int tid = threadIdx.x;
    if (tid < VV*3) sv[tid] = flocal[(size_t)bp*VV*3 + tid];
    __syncthreads();
    float pe = fpe[bp], ipe = finvpe[bp];
    float sc = fscale[bp];
    float m0 = fmean[3*bp+0], m1 = fmean[3*bp+1], m2 = fmean[3*bp+2];
    for (int dd = tid; dd < DD; dd += 256) {
        float xd = dirs[3*dd+0], yd = dirs[3*dd+1], zd = dirs[3*dd+2];
        // pts = x*scale + mean ; local = pts - mean (faithful op order)
        float lx = (xd * sc + m0) - m0;
        float ly = (yd * sc + m1) - m1;
        float lz = (zd * sc + m2) - m2;
        float n2 = clampf(lx*lx + ly*ly + lz*lz, 1e-40f, 1e40f);
        float invr = frsq(n2);
        float dx = lx * invr, dy = ly * invr, dz = lz * invr;

        float l2z[VV];
        float maxz = -1e38f;
        float zz[VV];
#pragma unroll
        for (int k = 0; k < VV; ++k) {
            float z = sv[3*k+0]*dx + sv[3*k+1]*dy + sv[3*k+2]*dz;
            zz[k] = z;
            maxz = fmaxf(maxz, z);
        }
        maxz = clampf(maxz, 1e-30f, 1e30f);
        float kk = frcp(maxz);
        float sum = 0.0f;
#pragma unroll
        for (int k = 0; k < VV; ++k) {
            float zm = clampf(fmaxf(zz[k], 0.0f) * kk, 1e-30f, 1e30f);
            float l2 = flog2(zm);
            l2z[k] = l2;
            sum += fexp2(pe * l2);
        }
        float l2sum = flog2(sum);
        float h = fexp2(l2sum * ipe);
        float s = clampf(h, 1e-30f, 1e30f);
        float l2s = flog2(s);
        float pem1 = pe - 1.0f;
        float sxx = 0.f, syy = 0.f, szz2 = 0.f;
#pragma unroll
        for (int k = 0; k < VV; ++k) {
            float dh = clampf(fexp2(pem1 * (l2z[k] - l2s)), 1e-30f, 1e30f);
            sxx += dh * sv[3*k+0];
            syy += dh * sv[3*k+1];
            szz2 += dh * sv[3*k+2];
        }
        sxx += m0; syy += m1; szz2 += m2;
        float* spp = fsurf + ((size_t)bp * DD + dd) * 3;
        spp[0] = sxx; spp[1] = syy; spp[2] = szz2;
        float* op = out4 + ((size_t)bp * DD + dd) * 3;
        op[0] = sxx; op[1] = syy; op[2] = szz2;
    }
}

// ---- overlap: P x P pairs per batch (f64 geometry, f32 support) ----
__global__ void __launch_bounds__(256) k_overlap(
        const float* __restrict__ flocal, const double* __restrict__ dmean,
        const float* __restrict__ fpe, const float* __restrict__ finvpe,
        float* __restrict__ out0)
{
    int b = blockIdx.x;
    __shared__ float  sv[PP*VV*3];
    __shared__ double smd[PP*3];
    __shared__ float  spe[PP];
    __shared__ float  sipe[PP];
    __shared__ float  sh[PP*PP];
    int tid = threadIdx.x;
    for (int t = tid; t < PP*VV*3; t += 256) sv[t] = flocal[(size_t)b*PP*VV*3 + t];
    if (tid < PP*3) smd[tid]  = dmean[(size_t)b*PP*3 + tid];
    if (tid < PP)  { spe[tid] = fpe[b*PP + tid]; sipe[tid] = finvpe[b*PP + tid]; }
    __syncthreads();
    int i = tid >> 4, j = tid & 15;
    double tx = smd[3*j+0] - smd[3*i+0];
    double ty = smd[3*j+1] - smd[3*i+1];
    double tz = smd[3*j+2] - smd[3*i+2];
    double dn2 = clampd(tx*tx + ty*ty + tz*tz, 1e-20, 1e20);
    double dn = sqrt(dn2);
    float dx, dy, dz;
    if (i == j) { dx = 1.0f; dy = 0.0f; dz = 0.0f; }
    else        { dx = (float)(tx/dn); dy = (float)(ty/dn); dz = (float)(tz/dn); }
    sh[tid] = spt_support_f(&sv[i*VV*3], spe[i], sipe[i], dx, dy, dz);
    __syncthreads();
    double sep = dn - (double)sh[i*16 + j] - (double)sh[j*16 + i];
    double ov = (i == j) ? 0.0 : fmax(-sep, 0.0);
    out0[(size_t)b*PP*PP + tid] = (float)ov;
}

// ---- generic distance kernel: dist = nrm - support (f32) ----
__global__ void __launch_bounds__(256) k_dist(
        const float* __restrict__ pts, int N,
        const float* __restrict__ flocal, const float* __restrict__ fmean,
        const float* __restrict__ fpe, const float* __restrict__ finvpe,
        float* __restrict__ outp)
{
    int bp = blockIdx.x;
    int b  = bp >> 4;
    __shared__ float sv[VV*3];
    int tid = threadIdx.x;
    if (tid < VV*3) sv[tid] = flocal[(size_t)bp*VV*3 + tid];
    __syncthreads();
    float pe = fpe[bp], ipe = finvpe[bp];
    float m0 = fmean[3*bp+0], m1 = fmean[3*bp+1], m2 = fmean[3*bp+2];
    int n = blockIdx.y * 256 + tid;
    if (n >= N) return;
    const float* pp = pts + ((size_t)b * N + n) * 3;
    float lx = pp[0] - m0;
    float ly = pp[1] - m1;
    float lz = pp[2] - m2;
    float n2 = clampf(lx*lx + ly*ly + lz*lz, 1e-40f, 1e40f);
    float invr = frsq(n2);
    float nrm = n2 * invr;                    // = sqrt(n2)
    float dx = lx * invr, dy = ly * invr, dz = lz * invr;
    float hs = spt_support_f(sv, pe, ipe, dx, dy, dz);
    outp[(size_t)bp * N + n] = nrm - hs;
}

// ---- surf distance: nf filter in f64 (sign-critical), support in f32 ----
__global__ void __launch_bounds__(256) k_surfdist(
        const float* __restrict__ fsurf, const float* __restrict__ dirs,
        const float* __restrict__ flocal, const double* __restrict__ dmean,
        const float* __restrict__ fmean,
        const float* __restrict__ fpe, const float* __restrict__ finvpe,
        const double* __restrict__ dscale,
        float* __restrict__ out3)
{
    int bp = blockIdx.x;
    int b  = bp >> 4;
    int i  = bp & 15;
    __shared__ float sv[VV*3];
    int tid = threadIdx.x;
    if (tid < VV*3) sv[tid] = flocal[(size_t)bp*VV*3 + tid];
    __syncthreads();
    float pe = fpe[bp], ipe = finvpe[bp];
    double sc = dscale[bp];
    double mi0 = dmean[3*bp+0], mi1 = dmean[3*bp+1], mi2 = dmean[3*bp+2];
    int q = blockIdx.y * 256 + tid;
    if (q >= PP*DD) return;
    int j  = q / DD;
    int dd = q - j * DD;
    // normal_i at direction dd (f64, faithful op order — sign decides 100-vs-dist)
    double xd = (double)dirs[3*dd+0], yd = (double)dirs[3*dd+1], zd = (double)dirs[3*dd+2];
    double nlx = (xd * sc + mi0) - mi0;
    double nly = (yd * sc + mi1) - mi1;
    double nlz = (zd * sc + mi2) - mi2;
    double nn2 = clampd(nlx*nlx + nly*nly + nlz*nlz, 1e-40, 1e40);
    double nnr = sqrt(nn2);
    const double* mj = dmean + (size_t)(b*PP + j) * 3;
    double tx = mj[0] - mi0, ty = mj[1] - mi1, tz = mj[2] - mi2;
    double nf = (tx*nlx + ty*nly + tz*nlz) / nnr;
    float dist;
    if (i == j || nf < 0.0) {
        dist = 100.0f;
    } else {
        float fm0 = fmean[3*bp+0], fm1 = fmean[3*bp+1], fm2 = fmean[3*bp+2];
        const float* sp = fsurf + ((size_t)b * PP * DD + q) * 3;
        float lx = sp[0] - fm0;
        float ly = sp[1] - fm1;
        float lz = sp[2] - fm2;
        float n2 = clampf(lx*lx + ly*ly + lz*lz, 1e-40f, 1e40f);
        float invr = frsq(n2);
        float nrm = n2 * invr;
        float dx = lx * invr, dy = ly * invr, dz = lz * invr;
        float hs = spt_support_f(sv, pe, ipe, dx, dy, dz);
        dist = nrm - hs;
    }
    out3[(size_t)bp * PP * DD + q] = dist;
}

extern "C" void kernel_launch(void* const* d_in, const int* in_sizes, int n_in,
                              void* d_out, int out_size, void* d_ws, size_t ws_size,
                              hipStream_t stream)
{
    // ---- runtime input binding by size (robust to ordering / extra DIRS input) ----
    const float* verts  = nullptr;
    const float* smooth = nullptr;
    const float* pcb    = nullptr;
    const float* nsb    = nullptr;
    const float* ob     = nullptr;
    const float* dirsin = nullptr;
    int Bv = 8, BP = 128, NPCv = 16384, NNSv = 8192, NOUTv = 8192;

    {
        int si = 0;
        for (int i = 1; i < n_in; ++i) if (in_sizes[i] < in_sizes[si]) si = i;
        int bp = in_sizes[si];
        bool ok = (bp > 0) && (bp % PP == 0);
        int rem[8]; int nrem = 0;
        const float* vcand = nullptr; const float* dcand = nullptr;
        if (ok) {
            for (int i = 0; i < n_in && i < 8; ++i) {
                if (i == si) continue;
                if (!vcand && in_sizes[i] == bp * VV * 3) { vcand = (const float*)d_in[i]; continue; }
                if (!dcand && in_sizes[i] == DD * 3)      { dcand = (const float*)d_in[i]; continue; }
                rem[nrem++] = i;
            }
        }
        if (ok && vcand && nrem == 3) {
            int pci = rem[0];
            for (int r = 1; r < 3; ++r) if (in_sizes[rem[r]] > in_sizes[pci]) pci = rem[r];
            int oth[2]; int no = 0;
            for (int r = 0; r < 3; ++r) if (rem[r] != pci) oth[no++] = rem[r];
            int B = bp / PP;
            int npc = in_sizes[pci] / (3 * B);
            int nns = in_sizes[oth[0]] / (3 * B);
            int nou = in_sizes[oth[1]] / (3 * B);
            if (npc > 0 && nns > 0 && nou > 0) {
                smooth = (const float*)d_in[si];
                verts  = vcand;
                dirsin = dcand;
                pcb    = (const float*)d_in[pci];
                nsb    = (const float*)d_in[oth[0]];
                ob     = (const float*)d_in[oth[1]];
                Bv = B; BP = bp; NPCv = npc; NNSv = nns; NOUTv = nou;
            }
        }
        if (!verts) {   // fallback: dict order, reference shapes
            verts  = (const float*)d_in[0];
            smooth = (const float*)d_in[1];
            pcb    = (const float*)d_in[2];
            nsb    = (const float*)d_in[3];
            ob     = (const float*)d_in[4];
            Bv = 8; BP = 128; NPCv = 16384; NNSv = 8192; NOUTv = 8192;
        }
    }

    // ---- workspace carve ----
    double* dmean  = (double*)d_ws;              // 3*BP f64
    double* dscale = dmean + 3*(size_t)BP;       // BP f64
    float*  fdirs  = (float*)(dscale + BP);      // 2058
    float*  fmean  = fdirs + DD*3;               // 3*BP
    float*  fpe    = fmean + 3*(size_t)BP;       // BP
    float*  finvpe = fpe + BP;                   // BP
    float*  fscale = finvpe + BP;                // BP
    float*  flocal = fscale + BP;                // 96*BP
    float*  fsurf  = flocal + 96*(size_t)BP;     // 3*DD*BP

    // ---- output offsets (f32 elements) ----
    float* out = (float*)d_out;
    size_t o0 = 0;
    size_t o1 = o0 + (size_t)Bv*PP*PP;
    size_t o2 = o1 + (size_t)BP*NPCv;
    size_t o3 = o2 + (size_t)BP*DD*3;
    size_t o4 = o3 + (size_t)BP*PP*DD;
    size_t o5 = o4 + (size_t)BP*DD*3;
    size_t o6 = o5 + (size_t)BP*NNSv;

    const float* dirs = dirsin ? dirsin : fdirs;
    if (!dirsin) k_dirs<<<dim3(3), 256, 0, stream>>>(fdirs);
    k_prep<<<dim3((BP + 127)/128), 128, 0, stream>>>(verts, smooth, dmean, fmean, flocal,
                                                     fpe, finvpe, BP);
    k_scale_x<<<dim3(BP), 256, 0, stream>>>(dirs, flocal, fpe, finvpe, dscale, fscale, out + o2);
    k_surfpts<<<dim3(BP), 256, 0, stream>>>(dirs, flocal, fmean, fpe, finvpe, fscale,
                                            fsurf, out + o4);
    k_overlap<<<dim3(Bv), 256, 0, stream>>>(flocal, dmean, fpe, finvpe, out + o0);
    k_dist<<<dim3(BP, (NPCv + 255)/256), 256, 0, stream>>>(pcb, NPCv, flocal, fmean, fpe, finvpe, out + o1);
    k_dist<<<dim3(BP, (NNSv + 255)/256), 256, 0, stream>>>(nsb, NNSv, flocal, fmean, fpe, finvpe, out + o5);
    k_dist<<<dim3(BP, (NOUTv + 255)/256), 256, 0, stream>>>(ob, NOUTv, flocal, fmean, fpe, finvpe, out + o6);
    k_surfdist<<<dim3(BP, (PP*DD + 255)/256), 256, 0, stream>>>(fsurf, dirs, flocal, dmean, fmean,
                                                                fpe, finvpe, dscale, out + o3);
}

// Round 7
// 145.347 us; speedup vs baseline: 5.1190x; 1.1019x over previous
//
#include <hip/hip_runtime.h>
#include <math.h>

#define PP 16
#define VV 32
#define DD 686

__device__ __forceinline__ float clampf(float x, float lo, float hi) {
    return fminf(fmaxf(x, lo), hi);
}
__device__ __forceinline__ double clampd(double x, double lo, double hi) {
    return fmin(fmax(x, lo), hi);
}
__device__ __forceinline__ float fexp2(float x) { return __builtin_amdgcn_exp2f(x); }
__device__ __forceinline__ float flog2(float x) { return __builtin_amdgcn_logf(x); }   // log base-2
__device__ __forceinline__ float frsq (float x) { return __builtin_amdgcn_rsqf(x); }

// un-normalized support: h = (sum_k max(z_k,eps)^pe)^(1/pe); 1-homogeneous in d.
// Safe in f32 for our ranges (|z|<=~3, pe<=10 -> z^pe <= 6e4). 4 partial sums for ILP.
__device__ __forceinline__ float spt_h(const float* __restrict__ sv, float pe, float inv_pe,
                                       float dx, float dy, float dz)
{
    float ss[4] = {0.f, 0.f, 0.f, 0.f};
#pragma unroll
    for (int k = 0; k < VV; ++k) {
        float z = sv[3*k+0]*dx + sv[3*k+1]*dy + sv[3*k+2]*dz;
        z = fmaxf(z, 1e-30f);
        ss[k & 3] += fexp2(pe * flog2(z));
    }
    float sum = (ss[0] + ss[1]) + (ss[2] + ss[3]);
    return fexp2(flog2(sum) * inv_pe);
}

// ---- directions (match numpy f64 linspace + trig, cast f32) ----
__global__ void k_dirs(float* __restrict__ dirs)
{
    int idx = blockIdx.x * blockDim.x + threadIdx.x;
    if (idx >= DD) return;
    int i, j;
    if (idx < 684)      { i = idx / 38 + 1; j = idx - (idx / 38) * 38; }
    else if (idx == 684){ i = 0;  j = 0; }
    else                { i = 19; j = 0; }
    const double pi = 3.14159265358979323846;
    double th1 = -pi * 0.5 + (double)i * (pi / 19.0);
    double th2 = -pi       + (double)j * (pi / 19.0);
    dirs[3*idx+0] = (float)(cos(th1) * cos(th2));
    dirs[3*idx+1] = (float)(cos(th1) * sin(th2));
    dirs[3*idx+2] = (float)(sin(th1));
}

// ---- per-shape prep ----
__global__ void k_prep(const float* __restrict__ verts, const float* __restrict__ smooth,
                       double* __restrict__ dmean, float* __restrict__ fmean,
                       float* __restrict__ flocal, float* __restrict__ fpe,
                       float* __restrict__ finvpe, int BP)
{
    int bp = blockIdx.x * blockDim.x + threadIdx.x;
    if (bp >= BP) return;
    const float* vv = verts + (size_t)bp * VV * 3;
    double sx = 0.0, sy = 0.0, sz = 0.0;
#pragma unroll
    for (int k = 0; k < VV; ++k) {
        sx += (double)vv[3*k+0];
        sy += (double)vv[3*k+1];
        sz += (double)vv[3*k+2];
    }
    double mx = sx / 32.0, my = sy / 32.0, mz = sz / 32.0;
    dmean[3*bp+0] = mx; dmean[3*bp+1] = my; dmean[3*bp+2] = mz;
    fmean[3*bp+0] = (float)mx; fmean[3*bp+1] = (float)my; fmean[3*bp+2] = (float)mz;
    float* lv = flocal + (size_t)bp * VV * 3;
#pragma unroll
    for (int k = 0; k < VV; ++k) {
        lv[3*k+0] = (float)((double)vv[3*k+0] - mx);
        lv[3*k+1] = (float)((double)vv[3*k+1] - my);
        lv[3*k+2] = (float)((double)vv[3*k+2] - mz);
    }
    float pe = smooth[bp];
    fpe[bp] = pe;
    finvpe[bp] = 1.0f / pe;
}

// ---- fused shape kernel: pass1 = support over 686 dirs (+x out, +scale),
//      pass2 = surf points via dhdz reusing log2(h) kept in registers.
//      Uses normalize(x*scale) == x (error ~1e-7, threshold 2.0).
__global__ void __launch_bounds__(256) k_shape(
        const float* __restrict__ dirs, const float* __restrict__ flocal,
        const float* __restrict__ fmean,
        const float* __restrict__ fpe, const float* __restrict__ finvpe,
        double* __restrict__ dscale,
        float* __restrict__ out2, float* __restrict__ fsurf, float* __restrict__ out4)
{
    int bp = blockIdx.x;
    __shared__ float sv[VV*3];
    __shared__ float red[4];
    int tid = threadIdx.x;
    if (tid < VV*3) sv[tid] = flocal[(size_t)bp*VV*3 + tid];
    __syncthreads();
    float pe = fpe[bp], ipe = finvpe[bp];
    float m0 = fmean[3*bp+0], m1 = fmean[3*bp+1], m2 = fmean[3*bp+2];

    float l2h_reg[3];   // log2(h) per handled dir (dd = tid + 256*i)
    float m = -1e38f;
#pragma unroll
    for (int it = 0; it < 3; ++it) {
        int dd = tid + 256*it;
        if (dd >= DD) break;
        float dx = dirs[3*dd+0], dy = dirs[3*dd+1], dz = dirs[3*dd+2];
        float ss[4] = {0.f,0.f,0.f,0.f};
#pragma unroll
        for (int k = 0; k < VV; ++k) {
            float z = sv[3*k+0]*dx + sv[3*k+1]*dy + sv[3*k+2]*dz;
            z = fmaxf(z, 1e-30f);
            ss[k & 3] += fexp2(pe * flog2(z));
        }
        float sum = (ss[0]+ss[1]) + (ss[2]+ss[3]);
        float l2h = flog2(sum) * ipe;
        l2h_reg[it] = l2h;
        m = fmaxf(m, fexp2(l2h));
        float* xp = out2 + ((size_t)bp * DD + dd) * 3;
        xp[0] = dx; xp[1] = dy; xp[2] = dz;
    }
#pragma unroll
    for (int o = 32; o > 0; o >>= 1) m = fmaxf(m, __shfl_down(m, o));
    if ((tid & 63) == 0) red[tid >> 6] = m;
    __syncthreads();
    if (tid == 0) {
        m = fmaxf(fmaxf(red[0], red[1]), fmaxf(red[2], red[3]));
        dscale[bp] = (double)clampf(m, 1e-10f, 10.0f);
    }

    // pass 2: surf points; d == x exactly, dhdz = exp2((pe-1)*(log2 z - log2 h))
    float pem1 = pe - 1.0f;
#pragma unroll
    for (int it = 0; it < 3; ++it) {
        int dd = tid + 256*it;
        if (dd >= DD) break;
        float dx = dirs[3*dd+0], dy = dirs[3*dd+1], dz = dirs[3*dd+2];
        float l2h = l2h_reg[it];
        float sxx = 0.f, syy = 0.f, szz = 0.f;
#pragma unroll
        for (int k = 0; k < VV; ++k) {
            float vx = sv[3*k+0], vy = sv[3*k+1], vz = sv[3*k+2];
            float z = vx*dx + vy*dy + vz*dz;
            z = fmaxf(z, 1e-30f);
            float dh = fexp2(pem1 * (flog2(z) - l2h));
            sxx += dh * vx; syy += dh * vy; szz += dh * vz;
        }
        sxx += m0; syy += m1; szz += m2;
        float* spp = fsurf + ((size_t)bp * DD + dd) * 3;
        spp[0] = sxx; spp[1] = syy; spp[2] = szz;
        float* op = out4 + ((size_t)bp * DD + dd) * 3;
        op[0] = sxx; op[1] = syy; op[2] = szz;
    }
}

// ---- overlap: P x P pairs per batch (f64 geometry, f32 support) ----
__global__ void __launch_bounds__(256) k_overlap(
        const float* __restrict__ flocal, const double* __restrict__ dmean,
        const float* __restrict__ fpe, const float* __restrict__ finvpe,
        float* __restrict__ out0)
{
    int b = blockIdx.x;
    __shared__ float  sv[PP*VV*3];
    __shared__ double smd[PP*3];
    __shared__ float  spe[PP];
    __shared__ float  sipe[PP];
    __shared__ float  sh[PP*PP];
    int tid = threadIdx.x;
    for (int t = tid; t < PP*VV*3; t += 256) sv[t] = flocal[(size_t)b*PP*VV*3 + t];
    if (tid < PP*3) smd[tid]  = dmean[(size_t)b*PP*3 + tid];
    if (tid < PP)  { spe[tid] = fpe[b*PP + tid]; sipe[tid] = finvpe[b*PP + tid]; }
    __syncthreads();
    int i = tid >> 4, j = tid & 15;
    double tx = smd[3*j+0] - smd[3*i+0];
    double ty = smd[3*j+1] - smd[3*i+1];
    double tz = smd[3*j+2] - smd[3*i+2];
    double dn2 = clampd(tx*tx + ty*ty + tz*tz, 1e-20, 1e20);
    double dn = sqrt(dn2);
    float dx, dy, dz;
    if (i == j) { dx = 1.0f; dy = 0.0f; dz = 0.0f; }
    else        { dx = (float)(tx/dn); dy = (float)(ty/dn); dz = (float)(tz/dn); }
    sh[tid] = spt_h(&sv[i*VV*3], spe[i], sipe[i], dx, dy, dz);
    __syncthreads();
    double sep = dn - (double)sh[i*16 + j] - (double)sh[j*16 + i];
    double ov = (i == j) ? 0.0 : fmax(-sep, 0.0);
    out0[(size_t)b*PP*PP + tid] = (float)ov;
}

// ---- merged distance kernel: 3 query sets in one launch ----
__global__ void __launch_bounds__(256) k_dist_all(
        const float* __restrict__ pc, int NPCv, int cPC,
        const float* __restrict__ ns, int NNSv, int cNS,
        const float* __restrict__ ob, int NOUTv,
        const float* __restrict__ flocal, const float* __restrict__ fmean,
        const float* __restrict__ fpe, const float* __restrict__ finvpe,
        float* __restrict__ out1, float* __restrict__ out5, float* __restrict__ out6)
{
    int bp = blockIdx.x;
    int b  = bp >> 4;
    __shared__ float sv[VV*3];
    int tid = threadIdx.x;
    if (tid < VV*3) sv[tid] = flocal[(size_t)bp*VV*3 + tid];
    __syncthreads();
    float pe = fpe[bp], ipe = finvpe[bp];
    float m0 = fmean[3*bp+0], m1 = fmean[3*bp+1], m2 = fmean[3*bp+2];

    int y = blockIdx.y;
    const float* pts; int N; float* outp;
    if (y < cPC)            { pts = pc; N = NPCv;  outp = out1; }
    else if ((y -= cPC) < cNS) { pts = ns; N = NNSv;  outp = out5; }
    else                    { y -= cNS; pts = ob; N = NOUTv; outp = out6; }
    int n = y * 256 + tid;
    if (n >= N) return;
    const float* pp = pts + ((size_t)b * N + n) * 3;
    float lx = pp[0] - m0;
    float ly = pp[1] - m1;
    float lz = pp[2] - m2;
    float n2 = clampf(lx*lx + ly*ly + lz*lz, 1e-40f, 1e40f);
    float invr = frsq(n2);
    float nrm = n2 * invr;                        // sqrt(n2)
    float hs = spt_h(sv, pe, ipe, lx, ly, lz) * invr;   // homogeneity
    outp[(size_t)bp * N + n] = nrm - hs;
}

// ---- surf distance: nf filter in f64 (sign-critical), support in f32 ----
__global__ void __launch_bounds__(256) k_surfdist(
        const float* __restrict__ fsurf, const float* __restrict__ dirs,
        const float* __restrict__ flocal, const double* __restrict__ dmean,
        const float* __restrict__ fmean,
        const float* __restrict__ fpe, const float* __restrict__ finvpe,
        const double* __restrict__ dscale,
        float* __restrict__ out3)
{
    int bp = blockIdx.x;
    int b  = bp >> 4;
    int i  = bp & 15;
    __shared__ float sv[VV*3];
    int tid = threadIdx.x;
    if (tid < VV*3) sv[tid] = flocal[(size_t)bp*VV*3 + tid];
    __syncthreads();
    float pe = fpe[bp], ipe = finvpe[bp];
    double sc = dscale[bp];
    double mi0 = dmean[3*bp+0], mi1 = dmean[3*bp+1], mi2 = dmean[3*bp+2];
    int q = blockIdx.y * 256 + tid;
    if (q >= PP*DD) return;
    int j  = q / DD;
    int dd = q - j * DD;
    // normal_i at direction dd (f64, faithful op order — sign decides 100-vs-dist)
    double xd = (double)dirs[3*dd+0], yd = (double)dirs[3*dd+1], zd = (double)dirs[3*dd+2];
    double nlx = (xd * sc + mi0) - mi0;
    double nly = (yd * sc + mi1) - mi1;
    double nlz = (zd * sc + mi2) - mi2;
    double nn2 = clampd(nlx*nlx + nly*nly + nlz*nlz, 1e-40, 1e40);
    double nnr = sqrt(nn2);
    const double* mj = dmean + (size_t)(b*PP + j) * 3;
    double tx = mj[0] - mi0, ty = mj[1] - mi1, tz = mj[2] - mi2;
    double nf = (tx*nlx + ty*nly + tz*nlz) / nnr;
    float dist;
    if (i == j || nf < 0.0) {
        dist = 100.0f;
    } else {
        float fm0 = fmean[3*bp+0], fm1 = fmean[3*bp+1], fm2 = fmean[3*bp+2];
        const float* sp = fsurf + ((size_t)b * PP * DD + q) * 3;
        float lx = sp[0] - fm0;
        float ly = sp[1] - fm1;
        float lz = sp[2] - fm2;
        float n2 = clampf(lx*lx + ly*ly + lz*lz, 1e-40f, 1e40f);
        float invr = frsq(n2);
        float nrm = n2 * invr;
        float hs = spt_h(sv, pe, ipe, lx, ly, lz) * invr;
        dist = nrm - hs;
    }
    out3[(size_t)bp * PP * DD + q] = dist;
}

extern "C" void kernel_launch(void* const* d_in, const int* in_sizes, int n_in,
                              void* d_out, int out_size, void* d_ws, size_t ws_size,
                              hipStream_t stream)
{
    // ---- runtime input binding by size ----
    const float* verts  = nullptr;
    const float* smooth = nullptr;
    const float* pcb    = nullptr;
    const float* nsb    = nullptr;
    const float* ob     = nullptr;
    const float* dirsin = nullptr;
    int Bv = 8, BP = 128, NPCv = 16384, NNSv = 8192, NOUTv = 8192;

    {
        int si = 0;
        for (int i = 1; i < n_in; ++i) if (in_sizes[i] < in_sizes[si]) si = i;
        int bp = in_sizes[si];
        bool ok = (bp > 0) && (bp % PP == 0);
        int rem[8]; int nrem = 0;
        const float* vcand = nullptr; const float* dcand = nullptr;
        if (ok) {
            for (int i = 0; i < n_in && i < 8; ++i) {
                if (i == si) continue;
                if (!vcand && in_sizes[i] == bp * VV * 3) { vcand = (const float*)d_in[i]; continue; }
                if (!dcand && in_sizes[i] == DD * 3)      { dcand = (const float*)d_in[i]; continue; }
                rem[nrem++] = i;
            }
        }
        if (ok && vcand && nrem == 3) {
            int pci = rem[0];
            for (int r = 1; r < 3; ++r) if (in_sizes[rem[r]] > in_sizes[pci]) pci = rem[r];
            int oth[2]; int no = 0;
            for (int r = 0; r < 3; ++r) if (rem[r] != pci) oth[no++] = rem[r];
            int B = bp / PP;
            int npc = in_sizes[pci] / (3 * B);
            int nns = in_sizes[oth[0]] / (3 * B);
            int nou = in_sizes[oth[1]] / (3 * B);
            if (npc > 0 && nns > 0 && nou > 0) {
                smooth = (const float*)d_in[si];
                verts  = vcand;
                dirsin = dcand;
                pcb    = (const float*)d_in[pci];
                nsb    = (const float*)d_in[oth[0]];
                ob     = (const float*)d_in[oth[1]];
                Bv = B; BP = bp; NPCv = npc; NNSv = nns; NOUTv = nou;
            }
        }
        if (!verts) {   // fallback: dict order, reference shapes
            verts  = (const float*)d_in[0];
            smooth = (const float*)d_in[1];
            pcb    = (const float*)d_in[2];
            nsb    = (const float*)d_in[3];
            ob     = (const float*)d_in[4];
            Bv = 8; BP = 128; NPCv = 16384; NNSv = 8192; NOUTv = 8192;
        }
    }

    // ---- workspace carve ----
    double* dmean  = (double*)d_ws;              // 3*BP f64
    double* dscale = dmean + 3*(size_t)BP;       // BP f64
    float*  fdirs  = (float*)(dscale + BP);      // 2058
    float*  fmean  = fdirs + DD*3;               // 3*BP
    float*  fpe    = fmean + 3*(size_t)BP;       // BP
    float*  finvpe = fpe + BP;                   // BP
    float*  flocal = finvpe + BP;                // 96*BP
    float*  fsurf  = flocal + 96*(size_t)BP;     // 3*DD*BP

    // ---- output offsets (f32 elements) ----
    float* out = (float*)d_out;
    size_t o0 = 0;
    size_t o1 = o0 + (size_t)Bv*PP*PP;
    size_t o2 = o1 + (size_t)BP*NPCv;
    size_t o3 = o2 + (size_t)BP*DD*3;
    size_t o4 = o3 + (size_t)BP*PP*DD;
    size_t o5 = o4 + (size_t)BP*DD*3;
    size_t o6 = o5 + (size_t)BP*NNSv;

    const float* dirs = dirsin ? dirsin : fdirs;
    if (!dirsin) k_dirs<<<dim3(3), 256, 0, stream>>>(fdirs);
    k_prep<<<dim3((BP + 127)/128), 128, 0, stream>>>(verts, smooth, dmean, fmean, flocal,
                                                     fpe, finvpe, BP);
    k_shape<<<dim3(BP), 256, 0, stream>>>(dirs, flocal, fmean, fpe, finvpe, dscale,
                                          out + o2, fsurf, out + o4);
    k_overlap<<<dim3(Bv), 256, 0, stream>>>(flocal, dmean, fpe, finvpe, out + o0);
    int cPC = (NPCv + 255)/256, cNS = (NNSv + 255)/256, cOU = (NOUTv + 255)/256;
    k_dist_all<<<dim3(BP, cPC + cNS + cOU), 256, 0, stream>>>(
        pcb, NPCv, cPC, nsb, NNSv, cNS, ob, NOUTv,
        flocal, fmean, fpe, finvpe, out + o1, out + o5, out + o6);
    k_surfdist<<<dim3(BP, (PP*DD + 255)/256), 256, 0, stream>>>(fsurf, dirs, flocal, dmean, fmean,
                                                                fpe, finvpe, dscale, out + o3);
}